// Round 5
// baseline (132.004 us; speedup 1.0000x reference)
//
#include <hip/hip_runtime.h>
#include <math.h>

#define H 512
#define W 512
#define BAND 4
#define NQ 11   // 0:s0(mask) 1-4:s1i..s4i 5-8:s1o..s4o 9:tex 10:shape

__device__ __forceinline__ float2 shfl_up1_f2(float2 v, int lane) {
    float2 r;
    r.x = __shfl_up(v.x, 1);
    r.y = __shfl_up(v.y, 1);
    if (lane == 0) { r.x = 0.0f; r.y = 0.0f; }
    return r;
}
__device__ __forceinline__ float2 shfl_dn1_f2(float2 v, int lane) {
    float2 r;
    r.x = __shfl_down(v.x, 1);
    r.y = __shfl_down(v.y, 1);
    if (lane == 63) { r.x = 0.0f; r.y = 0.0f; }
    return r;
}

__device__ __forceinline__ float2 pk_add(float2 a, float2 b) { return make_float2(a.x + b.x, a.y + b.y); }
__device__ __forceinline__ float2 pk_sub(float2 a, float2 b) { return make_float2(a.x - b.x, a.y - b.y); }
__device__ __forceinline__ float2 pk_mul(float2 a, float2 b) { return make_float2(a.x * b.x, a.y * b.y); }
__device__ __forceinline__ float2 pk_muls(float2 a, float s) { return make_float2(a.x * s, a.y * s); }
__device__ __forceinline__ float2 pk_fma(float2 a, float2 b, float2 c) {
    return make_float2(fmaf(a.x, b.x, c.x), fmaf(a.y, b.y, c.y));
}

// load one row of BOTH images, interleaved: dst[j] = (inp[y][x0+j], outp[y][x0+j])
__device__ __forceinline__ void load_row_pk(const float* __restrict__ inp,
                                            const float* __restrict__ outp,
                                            size_t off, int y, int x0, float2* dst) {
    if (y < 0 || y >= H) {
        #pragma unroll
        for (int j = 0; j < 8; j++) dst[j] = make_float2(0.0f, 0.0f);
    } else {
        const float4* pi = reinterpret_cast<const float4*>(inp  + off + (size_t)y * W + x0);
        const float4* po = reinterpret_cast<const float4*>(outp + off + (size_t)y * W + x0);
        float4 a = pi[0], b = pi[1];
        float4 c = po[0], d = po[1];
        dst[0] = make_float2(a.x, c.x); dst[1] = make_float2(a.y, c.y);
        dst[2] = make_float2(a.z, c.z); dst[3] = make_float2(a.w, c.w);
        dst[4] = make_float2(b.x, d.x); dst[5] = make_float2(b.y, d.y);
        dst[6] = make_float2(b.z, d.z); dst[7] = make_float2(b.w, d.w);
    }
}

__device__ __forceinline__ void load_mask_row(const float* __restrict__ mask, size_t off,
                                              int y, int x0, float* dst) {
    const float4* p = reinterpret_cast<const float4*>(mask + off + (size_t)y * W + x0);
    float4 a = p[0];
    float4 b = p[1];
    dst[0] = a.x; dst[1] = a.y; dst[2] = a.z; dst[3] = a.w;
    dst[4] = b.x; dst[5] = b.y; dst[6] = b.z; dst[7] = b.w;
}

// 1 wave per block: waves retire independently (no end-of-block barrier coupling),
// finer residency granularity for the scheduler. Register prefetch pipeline gives
// ~1 full iteration (~500 cyc) of load-to-use distance.
// NOTE: no min-waves arg — round 2 showed forcing it causes catastrophic spills.
__global__ __launch_bounds__(64) void radiomics_main(
    const float* __restrict__ inp, const float* __restrict__ outp,
    const float* __restrict__ mask, double* __restrict__ partials)
{
    const int lane = threadIdx.x;                // 0..63, one wave per block
    const int gwave = blockIdx.x;
    const int b = gwave >> 7;                    // gwave / (H/BAND = 128)
    const int band = gwave & 127;
    const int y0 = band * BAND;
    const size_t off = (size_t)b * H * W;
    const int x0 = lane * 8;

    // rolling 3-row packed window (x=inp, y=outp) + prefetch row + mask rows
    float2 P[8], C[8], N[8], R[8];
    float  Mk[8], Mn[8];

    load_row_pk(inp, outp, off, y0 - 1, x0, P);
    load_row_pk(inp, outp, off, y0,     x0, C);
    load_row_pk(inp, outp, off, y0 + 1, x0, N);
    load_mask_row(mask, off, y0, x0, Mk);

    float  acc0 = 0.0f, accT = 0.0f, accS = 0.0f;
    float2 am1 = make_float2(0,0), am2 = make_float2(0,0);
    float2 am3 = make_float2(0,0), am4 = make_float2(0,0);

    const float inv9 = 1.0f / 9.0f;

    #pragma unroll
    for (int i = 0; i < BAND; i++) {
        // ---- software prefetch: issue next iteration's loads FIRST ----
        if (i < BAND - 1) {
            load_row_pk(inp, outp, off, y0 + i + 2, x0, R);   // next N
            load_mask_row(mask, off, y0 + i + 1, x0, Mn);     // next mask row
        }

        // ---- compute row y0+i from P/C/N (loads for it completed last iter) ----
        float2 s1[8], s2[8];
        #pragma unroll
        for (int j = 0; j < 8; j++) {
            s1[j] = pk_add(pk_add(P[j], C[j]), N[j]);
            s2[j] = pk_fma(P[j], P[j], pk_fma(C[j], C[j], pk_mul(N[j], N[j])));
        }
        // horizontal halos via cross-lane shuffle; lane0/63 are true zero padding
        float2 h1l = shfl_up1_f2(s1[7], lane), h1r = shfl_dn1_f2(s1[0], lane);
        float2 h2l = shfl_up1_f2(s2[7], lane), h2r = shfl_dn1_f2(s2[0], lane);
        float2 hcl = shfl_up1_f2(C[7],  lane), hcr = shfl_dn1_f2(C[0],  lane);

        #pragma unroll
        for (int j = 0; j < 8; j++) {
            float2 l1 = (j == 0) ? h1l : s1[j-1];
            float2 r1 = (j == 7) ? h1r : s1[j+1];
            float2 l2 = (j == 0) ? h2l : s2[j-1];
            float2 r2 = (j == 7) ? h2r : s2[j+1];
            float2 mn = pk_muls(pk_add(pk_add(l1, s1[j]), r1), inv9);
            float2 e2 = pk_muls(pk_add(pk_add(l2, s2[j]), r2), inv9);
            float2 tv = pk_fma(make_float2(-mn.x, -mn.y), mn, e2);   // E[x^2]-E[x]^2
            float2 cl = (j == 0) ? hcl : C[j-1];
            float2 cr = (j == 7) ? hcr : C[j+1];
            // up+down+left+right-4c = (s1-C) + cl + cr - 4C
            float2 lp = pk_sub(pk_add(pk_add(pk_sub(s1[j], C[j]), cl), cr),
                               pk_muls(C[j], 4.0f));
            float m = Mk[j];
            accT += fabsf(tv.y * m - tv.x * m);
            accS += fabsf(lp.y * m - lp.x * m);
            acc0 += m;
            // raw masked moments, packed (x=inp, y=outp)
            float2 X = C[j];
            float2 t = pk_muls(X, m);
            am1 = pk_add(am1, t); t = pk_mul(t, X);
            am2 = pk_add(am2, t); t = pk_mul(t, X);
            am3 = pk_add(am3, t); t = pk_mul(t, X);
            am4 = pk_add(am4, t);
        }

        // ---- shift window into prefetched data ----
        if (i < BAND - 1) {
            #pragma unroll
            for (int j = 0; j < 8; j++) { P[j] = C[j]; C[j] = N[j]; N[j] = R[j]; Mk[j] = Mn[j]; }
        }
    }

    // wave-level fp32 butterfly reduce; lane 0 writes the 11 fp64 partials
    float acc[NQ] = { acc0, am1.x, am2.x, am3.x, am4.x,
                            am1.y, am2.y, am3.y, am4.y, accT, accS };
    #pragma unroll
    for (int q = 0; q < NQ; q++) {
        float v = acc[q];
        #pragma unroll
        for (int o = 32; o > 0; o >>= 1) v += __shfl_down(v, o);
        acc[q] = v;
    }
    if (lane == 0) {
        #pragma unroll
        for (int q = 0; q < NQ; q++)
            partials[(size_t)gwave * NQ + q] = (double)acc[q];
    }
}

__global__ __launch_bounds__(256) void radiomics_final(
    const double* __restrict__ partials, int nblk, float* __restrict__ out4, double inv_n)
{
    const int tid = threadIdx.x;
    const int lane = tid & 63;
    const int w = tid >> 6;
    double q[NQ];
    #pragma unroll
    for (int k = 0; k < NQ; k++) q[k] = 0.0;
    for (int i = tid; i < nblk; i += 256) {
        #pragma unroll
        for (int k = 0; k < NQ; k++) q[k] += partials[(size_t)i * NQ + k];
    }
    #pragma unroll
    for (int k = 0; k < NQ; k++) {
        #pragma unroll
        for (int o = 32; o > 0; o >>= 1) q[k] += __shfl_down(q[k], o);
    }
    __shared__ double red[4][NQ];
    if (lane == 0) {
        #pragma unroll
        for (int k = 0; k < NQ; k++) red[w][k] = q[k];
    }
    __syncthreads();
    if (tid == 0) {
        double s[NQ];
        #pragma unroll
        for (int k = 0; k < NQ; k++) s[k] = red[0][k] + red[1][k] + red[2][k] + red[3][k];
        const double EPS = 1e-8;
        double S0 = s[0];
        double ms = S0 + EPS;
        double im = s[1] / ms, om = s[5] / ms;
        double im2 = im * im, im3 = im2 * im, im4 = im2 * im2;
        double om2 = om * om, om3 = om2 * om, om4 = om2 * om2;
        double di2 = s[2] - 2.0*im*s[1] + im2*S0;
        double do2 = s[6] - 2.0*om*s[5] + om2*S0;
        double iv = di2 / ms, ov = do2 / ms;
        double di3 = s[3] - 3.0*im*s[2] + 3.0*im2*s[1] - im3*S0;
        double do3 = s[7] - 3.0*om*s[6] + 3.0*om2*s[5] - om3*S0;
        double isk = di3 / (ms * (iv * sqrt(iv) + EPS));
        double osk = do3 / (ms * (ov * sqrt(ov) + EPS));
        double di4 = s[4] - 4.0*im*s[3] + 6.0*im2*s[2] - 4.0*im3*s[1] + im4*S0;
        double do4 = s[8] - 4.0*om*s[7] + 6.0*om2*s[6] - 4.0*om3*s[5] + om4*S0;
        double iku = di4 / (ms * (iv * iv + EPS));
        double oku = do4 / (ms * (ov * ov + EPS));
        double intensity = (im-om)*(im-om) + (iv-ov)*(iv-ov)
                         + (isk-osk)*(isk-osk) + (iku-oku)*(iku-oku);
        double texture = s[9]  * inv_n;
        double shape   = s[10] * inv_n;
        // TEXTURE_W=1.0, SHAPE_W=0.5, INTENSITY_W=1.0
        double total = intensity + texture + 0.5 * shape;
        out4[0] = (float)intensity;
        out4[1] = (float)texture;
        out4[2] = (float)shape;
        out4[3] = (float)total;
    }
}

extern "C" void kernel_launch(void* const* d_in, const int* in_sizes, int n_in,
                              void* d_out, int out_size, void* d_ws, size_t ws_size,
                              hipStream_t stream) {
    const float* inp  = (const float*)d_in[0];
    const float* outp = (const float*)d_in[1];
    const float* mask = (const float*)d_in[2];
    const int total = in_sizes[0];             // 32*1*512*512
    const int nimg  = total / (H * W);         // 32
    const int nwaves = nimg * (H / BAND);      // 4096
    double* partials = (double*)d_ws;          // nwaves*NQ doubles, fully overwritten

    radiomics_main<<<nwaves, 64, 0, stream>>>(inp, outp, mask, partials);
    const double inv_n = 1.0 / (double)total;
    radiomics_final<<<1, 256, 0, stream>>>(partials, nwaves, (float*)d_out, inv_n);
}

// Round 6
// 131.130 us; speedup vs baseline: 1.0067x; 1.0067x over previous
//
#include <hip/hip_runtime.h>
#include <math.h>

#define H 512
#define W 512
#define BAND 8            // rows computed per block
#define STAGE (BAND + 2)  // rows staged per image (with halo)
#define NQ 11             // 0:s0 1-4:s1i..s4i 5-8:s1o..s4o 9:tex 10:shape

typedef __attribute__((address_space(3))) void       lds_void;
typedef const __attribute__((address_space(1))) void g_void;

// async global->LDS DMA, 16 B/lane: lane i's 16 B lands at l + i*16.
// gptr must be g + lane*16 for a contiguous row segment (wave-uniform LDS base).
__device__ __forceinline__ void async_copy16(const float* g, float* l) {
    __builtin_amdgcn_global_load_lds((g_void*)g, (lds_void*)l, 16, 0, 0);
}

// read 8 px + 1-col halo each side from an LDS row; x0 is lane*8 (32B aligned)
__device__ __forceinline__ void load10(const float* row, int x0, float* a) {
    float4 u = *(const float4*)&row[x0];
    float4 v = *(const float4*)&row[x0 + 4];
    a[0] = (x0 == 0) ? 0.0f : row[x0 - 1];
    a[1] = u.x; a[2] = u.y; a[3] = u.z; a[4] = u.w;
    a[5] = v.x; a[6] = v.y; a[7] = v.z; a[8] = v.w;
    a[9] = (x0 + 8 == W) ? 0.0f : row[x0 + 8];
}

// Cooperative-LDS structure (m97 pattern): 40 KB static LDS = exactly 4 blocks/CU.
// Async DMA staging holds ZERO VGPRs -> deep MLP; one barrier per block; blocks
// pipeline on the CU (one drains while three compute).
__global__ __launch_bounds__(256) void radiomics_main(
    const float* __restrict__ inp, const float* __restrict__ outp,
    const float* __restrict__ mask, double* __restrict__ partials)
{
    __shared__ float lds[2][STAGE][W];          // 2*10*2048 B = 40960 B

    const int tid  = threadIdx.x;
    const int lane = tid & 63;
    const int wib  = tid >> 6;                  // wave in block (0..3)
    const int blk  = blockIdx.x;
    const int b    = blk >> 6;                  // image (64 bands/image)
    const int band = blk & 63;
    const int y0   = band * BAND;
    const size_t off = (size_t)b * H * W;
    const int x0   = lane * 8;

    // ---- stage 10 rows x 2 images: 40 segments of 1 KB, 10 per wave ----
    for (int s = wib; s < 2 * STAGE * 2; s += 4) {
        const int img = s / (2 * STAGE);
        const int rem = s - img * (2 * STAGE);
        const int rs  = rem >> 1;               // stage row 0..9
        const int g   = rem & 1;                // 1 KB segment in row
        const int y   = y0 - 1 + rs;
        float* dst = &lds[img][rs][g * 256];
        if (y < 0 || y >= H) {
            *(float4*)&dst[lane * 4] = make_float4(0.f, 0.f, 0.f, 0.f);
        } else {
            const float* src = (img ? outp : inp) + off + (size_t)y * W + g * 256 + lane * 4;
            async_copy16(src, dst);
        }
    }

    // ---- mask rows for this wave's 2 compute rows (regular register loads) ----
    const int r0 = y0 + 2 * wib;
    float Mk[16];
    {
        const float4* p = (const float4*)(mask + off + (size_t)r0 * W + x0);
        float4 a = p[0], c = p[1];
        const float4* q = (const float4*)(mask + off + (size_t)(r0 + 1) * W + x0);
        float4 d = q[0], e = q[1];
        Mk[0]=a.x; Mk[1]=a.y; Mk[2]=a.z; Mk[3]=a.w; Mk[4]=c.x; Mk[5]=c.y; Mk[6]=c.z; Mk[7]=c.w;
        Mk[8]=d.x; Mk[9]=d.y; Mk[10]=d.z; Mk[11]=d.w; Mk[12]=e.x; Mk[13]=e.y; Mk[14]=e.z; Mk[15]=e.w;
    }

    __syncthreads();   // drains vmcnt (DMA + mask) and lgkmcnt (zero-fill)

    const float inv9 = 1.0f / 9.0f;
    float acc[NQ];
    #pragma unroll
    for (int q = 0; q < NQ; q++) acc[q] = 0.0f;

    #pragma unroll
    for (int cr = 0; cr < 2; cr++) {
        const int rs = 2 * wib + cr + 1;        // stage index of computed row
        const float* mrow = &Mk[cr * 8];
        float tvI[8], lpI[8];

        // ---- image 0: texture/laplacian + input moments ----
        {
            float A[10], B[10], C[10];
            load10(lds[0][rs - 1], x0, A);
            load10(lds[0][rs],     x0, B);
            load10(lds[0][rs + 1], x0, C);
            float c1[10], c2[10];
            #pragma unroll
            for (int j = 0; j < 10; j++) {
                c1[j] = A[j] + B[j] + C[j];
                c2[j] = fmaf(A[j], A[j], fmaf(B[j], B[j], C[j] * C[j]));
            }
            #pragma unroll
            for (int j = 0; j < 8; j++) {
                float s1 = c1[j] + c1[j+1] + c1[j+2];
                float s2 = c2[j] + c2[j+1] + c2[j+2];
                float mn = s1 * inv9;
                tvI[j] = fmaf(-mn, mn, s2 * inv9);
                lpI[j] = A[j+1] + C[j+1] + B[j] + B[j+2] - 4.0f * B[j+1];
                float m = mrow[j];
                acc[0] += m;
                float x = B[j+1];
                float t = x * m; acc[1] += t; t *= x; acc[2] += t; t *= x; acc[3] += t; t *= x; acc[4] += t;
            }
        }
        // ---- image 1: diffs vs tvI/lpI + output moments ----
        {
            float A[10], B[10], C[10];
            load10(lds[1][rs - 1], x0, A);
            load10(lds[1][rs],     x0, B);
            load10(lds[1][rs + 1], x0, C);
            float c1[10], c2[10];
            #pragma unroll
            for (int j = 0; j < 10; j++) {
                c1[j] = A[j] + B[j] + C[j];
                c2[j] = fmaf(A[j], A[j], fmaf(B[j], B[j], C[j] * C[j]));
            }
            #pragma unroll
            for (int j = 0; j < 8; j++) {
                float s1 = c1[j] + c1[j+1] + c1[j+2];
                float s2 = c2[j] + c2[j+1] + c2[j+2];
                float mn = s1 * inv9;
                float tv = fmaf(-mn, mn, s2 * inv9);
                float lp = A[j+1] + C[j+1] + B[j] + B[j+2] - 4.0f * B[j+1];
                float m = mrow[j];
                acc[9]  += fabsf(tv * m - tvI[j] * m);
                acc[10] += fabsf(lp * m - lpI[j] * m);
                float x = B[j+1];
                float t = x * m; acc[5] += t; t *= x; acc[6] += t; t *= x; acc[7] += t; t *= x; acc[8] += t;
            }
        }
    }

    // ---- wave shuffle-reduce, then block reduce reusing the staging LDS ----
    #pragma unroll
    for (int q = 0; q < NQ; q++) {
        float v = acc[q];
        #pragma unroll
        for (int o = 32; o > 0; o >>= 1) v += __shfl_down(v, o);
        acc[q] = v;
    }
    __syncthreads();                  // all waves done reading staged data
    float* rf = (float*)lds;
    if (lane == 0) {
        #pragma unroll
        for (int q = 0; q < NQ; q++) rf[wib * NQ + q] = acc[q];
    }
    __syncthreads();
    if (tid < NQ) {
        double s = (double)rf[tid] + (double)rf[NQ + tid]
                 + (double)rf[2 * NQ + tid] + (double)rf[3 * NQ + tid];
        partials[(size_t)blk * NQ + tid] = s;
    }
}

__global__ __launch_bounds__(256) void radiomics_final(
    const double* __restrict__ partials, int nblk, float* __restrict__ out4, double inv_n)
{
    const int tid = threadIdx.x;
    const int lane = tid & 63;
    const int w = tid >> 6;
    double q[NQ];
    #pragma unroll
    for (int k = 0; k < NQ; k++) q[k] = 0.0;
    for (int i = tid; i < nblk; i += 256) {
        #pragma unroll
        for (int k = 0; k < NQ; k++) q[k] += partials[(size_t)i * NQ + k];
    }
    #pragma unroll
    for (int k = 0; k < NQ; k++) {
        #pragma unroll
        for (int o = 32; o > 0; o >>= 1) q[k] += __shfl_down(q[k], o);
    }
    __shared__ double red[4][NQ];
    if (lane == 0) {
        #pragma unroll
        for (int k = 0; k < NQ; k++) red[w][k] = q[k];
    }
    __syncthreads();
    if (tid == 0) {
        double s[NQ];
        #pragma unroll
        for (int k = 0; k < NQ; k++) s[k] = red[0][k] + red[1][k] + red[2][k] + red[3][k];
        const double EPS = 1e-8;
        double S0 = s[0];
        double ms = S0 + EPS;
        double im = s[1] / ms, om = s[5] / ms;
        double im2 = im * im, im3 = im2 * im, im4 = im2 * im2;
        double om2 = om * om, om3 = om2 * om, om4 = om2 * om2;
        double di2 = s[2] - 2.0*im*s[1] + im2*S0;
        double do2 = s[6] - 2.0*om*s[5] + om2*S0;
        double iv = di2 / ms, ov = do2 / ms;
        double di3 = s[3] - 3.0*im*s[2] + 3.0*im2*s[1] - im3*S0;
        double do3 = s[7] - 3.0*om*s[6] + 3.0*om2*s[5] - om3*S0;
        double isk = di3 / (ms * (iv * sqrt(iv) + EPS));
        double osk = do3 / (ms * (ov * sqrt(ov) + EPS));
        double di4 = s[4] - 4.0*im*s[3] + 6.0*im2*s[2] - 4.0*im3*s[1] + im4*S0;
        double do4 = s[8] - 4.0*om*s[7] + 6.0*om2*s[6] - 4.0*om3*s[5] + om4*S0;
        double iku = di4 / (ms * (iv * iv + EPS));
        double oku = do4 / (ms * (ov * ov + EPS));
        double intensity = (im-om)*(im-om) + (iv-ov)*(iv-ov)
                         + (isk-osk)*(isk-osk) + (iku-oku)*(iku-oku);
        double texture = s[9]  * inv_n;
        double shape   = s[10] * inv_n;
        // TEXTURE_W=1.0, SHAPE_W=0.5, INTENSITY_W=1.0
        double total = intensity + texture + 0.5 * shape;
        out4[0] = (float)intensity;
        out4[1] = (float)texture;
        out4[2] = (float)shape;
        out4[3] = (float)total;
    }
}

extern "C" void kernel_launch(void* const* d_in, const int* in_sizes, int n_in,
                              void* d_out, int out_size, void* d_ws, size_t ws_size,
                              hipStream_t stream) {
    const float* inp  = (const float*)d_in[0];
    const float* outp = (const float*)d_in[1];
    const float* mask = (const float*)d_in[2];
    const int total = in_sizes[0];             // 32*1*512*512
    const int nimg  = total / (H * W);         // 32
    const int nblk  = nimg * (H / BAND);       // 2048 blocks of 256 threads
    double* partials = (double*)d_ws;          // nblk*NQ doubles, fully overwritten

    radiomics_main<<<nblk, 256, 0, stream>>>(inp, outp, mask, partials);
    const double inv_n = 1.0 / (double)total;
    radiomics_final<<<1, 256, 0, stream>>>(partials, nblk, (float*)d_out, inv_n);
}